// Round 17
// baseline (835.608 us; speedup 1.0000x reference)
//
#include <hip/hip_runtime.h>

#define DEV static __device__ __forceinline__

typedef unsigned short u16;
typedef unsigned int u32;
typedef unsigned long long u64;
typedef float f32x4 __attribute__((ext_vector_type(4)));
typedef short bfrag __attribute__((ext_vector_type(8)));

#define FD 512
#define LV 4096
#define PV 5832   // 18^3

DEV float b2f(u16 u){ union{ u32 i; float f; } x; x.i = ((u32)u)<<16; return x.f; }
DEV u16 f2b(float f){ union{ float f; u32 i; } x; x.f = f; u32 r = x.i; r += 0x7fffu + ((r>>16)&1u); return (u16)(r>>16); }

DEV void g2l(const void* g, void* s){
  __builtin_amdgcn_global_load_lds((const __attribute__((address_space(1))) void*)g,
                                   (__attribute__((address_space(3))) void*)s, 16, 0, 0);
}

// ---------------- ws layout (bytes) ----------------
static const size_t o_wt  = 0;          // 27*512*512*2 conv weights bf16 [off][o][i]
static const size_t o_wq  = 14155776;   // 512*512*2
static const size_t o_ow  = 14680064;   // 512*512*2
static const size_t o_vpe = 15204352;   // 4096*512*4
static const size_t o_cpe = 23592960;   // 196*512*4
static const size_t o_gn  = 23994368;   // 512*4 stats
static const size_t o_mask= 23996416;   // 8*4096*4*8 = 1,048,576 mask bits (cube-linear)
static const size_t o_khb = 25044992;   // 1664*512*2 bf16 kh
static const size_t o_vhb = 26748928;   // 1664*512*2 bf16 vh
static const size_t o_hp  = 36841472;   // 8*5832*512*2 bf16 (padded GN+SiLU, all b)
static const size_t o_qb  = 84617216;   // 8*4096*512*2 bf16 (q; obuf alias)
static const size_t o_qh  = 118171648;  // 8*4096*512*2 bf16 (q-proj)
// kv-chain scratch aliases into o_qh region (dead until q-proj):
static const size_t o_skb = o_qh;               // 1664*768*2
static const size_t o_kwb = o_qh + 2555904;
static const size_t o_vwb = o_qh + 3342336;
static const size_t o_wkb = o_qh + 4128768;
static const size_t o_wvb = o_qh + 4653056;
static const size_t o_ktb = o_qh + 5177344;     // 1664*512*2
static const size_t o_vtb = o_qh + 6881280;
// end = 151,726,080

// ---------------- fused prep: LDS-staged conv-w transpose + 7 coalesced bf16 casts ----------------
__global__ __launch_bounds__(256) void prep_all(const float* __restrict__ convw,
    const float* __restrict__ ipw, const float* __restrict__ ow,
    const float* __restrict__ sketch, const float* __restrict__ kw, const float* __restrict__ vw,
    u16* __restrict__ wt, u16* __restrict__ Wq, u16* __restrict__ Ow, u16* __restrict__ Skb,
    u16* __restrict__ Kwb, u16* __restrict__ Vwb, u16* __restrict__ Wkb, u16* __restrict__ Wvb){
  __shared__ float raw[6912];
  int blk = blockIdx.x, t = threadIdx.x;
  if (blk < 1024){                      // conv weight transpose, coalesced both sides
    size_t base = (size_t)blk*6912;
    #pragma unroll
    for (int j=0;j<27;j++) raw[j*256 + t] = convw[base + j*256 + t];
    __syncthreads();
    int rowb = blk*256;
    #pragma unroll
    for (int k=0;k<27;k++) wt[(size_t)k*262144 + rowb + t] = f2b(raw[t*27 + k]);
  } else if (blk < 2048){ int i=(blk-1024)*256+t;  Wq[i]  = f2b(ipw[i]); }
  else if (blk < 3072){   int i=(blk-2048)*256+t;  Ow[i]  = f2b(ow[i]); }
  else if (blk < 7776){   int i=(blk-3072)*256+t;  if (i<1204224) Skb[i] = f2b(sketch[i]); }
  else if (blk < 9312){   int i=(blk-7776)*256+t;  Kwb[i] = f2b(kw[i]); }
  else if (blk < 10848){  int i=(blk-9312)*256+t;  Vwb[i] = f2b(vw[i]); }
  else if (blk < 11872){  int i=(blk-10848)*256+t; Wkb[i] = f2b(ipw[262144+i]); }
  else {                  int i=(blk-11872)*256+t; Wvb[i] = f2b(ipw[524288+i]); }
}

// ---------------- fused geometry prep: vpe + cpe + mask bits (cube-linear) ----------------
__global__ __launch_bounds__(256) void geom_prep(float* __restrict__ vpe, float* __restrict__ cpe,
    const float* __restrict__ proj, u64* __restrict__ maskb){
  int blk = blockIdx.x, t = threadIdx.x;
  if (blk < 4292){
    float* pe = (blk < 4096) ? vpe : cpe;
    int l = (blk < 4096) ? blk : blk - 4096;
    const float fac = -0.017988946039015984f; // -(log(10000)/512)
    float dt = expf((float)(2*t) * fac);
    float ang = (float)l * dt;
    pe[(size_t)l*FD + 2*t]     = sinf(ang);
    pe[(size_t)l*FD + 2*t + 1] = cosf(ang);
    return;
  }
  int idx = (blk-4292)*256 + t;   // 8*4096
  int b = idx >> 12, v = idx & 4095;
  float P[9];
  #pragma unroll
  for (int j=0;j<9;j++) P[j] = proj[b*9 + j];
  int zi=v>>8, yi=(v>>4)&15, xi=v&15;
  float pt0 = ((float)zi + 0.5f)/16.0f - 0.5f;
  float pt1 = ((float)yi + 0.5f)/16.0f - 0.5f;
  float pt2 = ((float)xi + 0.5f)/16.0f - 0.5f;
  float pc0 = __fadd_rn(__fadd_rn(__fmul_rn(P[0],pt0), __fmul_rn(P[1],pt1)), __fmul_rn(P[2],pt2));
  float pc1 = __fadd_rn(__fadd_rn(__fmul_rn(P[3],pt0), __fmul_rn(P[4],pt1)), __fmul_rn(P[5],pt2));
  float pc2 = __fadd_rn(__fadd_rn(__fmul_rn(P[6],pt0), __fmul_rn(P[7],pt1)), __fmul_rn(P[8],pt2));
  float r0 = __fdiv_rn(pc0, pc2);
  float r1 = __fdiv_rn(pc1, pc2);
  float px0 = fminf(fmaxf(rintf(r0), 0.f), 223.f);
  float px1 = fminf(fmaxf(rintf(r1), 0.f), 223.f);
  float x_idx = __fmul_rn(__fdiv_rn(__fadd_rn(__fmul_rn(2.f,px1),1.f), 224.f), 14.f) * 0.5f;
  float y_idx = __fmul_rn(__fdiv_rn(__fadd_rn(__fmul_rn(2.f,__fadd_rn(223.f,-px0)),1.f), 224.f), 14.f) * 0.5f;
  float ps0 = __fadd_rn(x_idx, -0.5f);
  float ps1 = __fadd_rn(y_idx, -0.5f);
  const float TH = 1.4999990463256836f;
  u64 abits[4] = {0,0,0,0};
  #pragma unroll 1
  for (int s=0;s<196;s++){
    int si = s/14, sj = s - si*14;
    float d0 = __fadd_rn(ps0, -(float)si);
    float d1 = __fadd_rn(ps1, -(float)sj);
    float dist = sqrtf(__fadd_rn(__fmul_rn(d0,d0), __fmul_rn(d1,d1)));
    if (!(fabsf(dist) > TH)) abits[s>>6] |= (1ull << (s&63));
  }
  int cube = (zi>>2)*16 + (yi>>2)*4 + (xi>>2);
  int cl = cube*64 + (zi&3)*16 + (yi&3)*4 + (xi&3);
  u64* out = maskb + ((size_t)b*4096 + cl)*4;
  out[0]=abits[0]; out[1]=abits[1]; out[2]=abits[2]; out[3]=abits[3];
}

// ---------------- group norm ----------------
__global__ __launch_bounds__(256) void gn_stats(const float* __restrict__ x, float* __restrict__ stats){
  int bg = blockIdx.x;
  const float* base = x + (size_t)bg*65536;
  float s=0.f, q=0.f;
  for (int i=threadIdx.x;i<65536;i+=256){ float v = base[i]; s+=v; q+=v*v; }
  #pragma unroll
  for (int off=32; off>0; off>>=1){ s += __shfl_xor(s,off); q += __shfl_xor(q,off); }
  __shared__ float red[8];
  int w = threadIdx.x>>6;
  if ((threadIdx.x&63)==0){ red[w*2]=s; red[w*2+1]=q; }
  __syncthreads();
  if (threadIdx.x==0){
    float S=red[0]+red[2]+red[4]+red[6];
    float Q=red[1]+red[3]+red[5]+red[7];
    float m = S*(1.f/65536.f);
    float var = Q*(1.f/65536.f) - m*m;
    stats[bg] = m;
    stats[256+bg] = rsqrtf(var + 1e-5f);
  }
}

// GN+SiLU -> padded channels-last bf16, LDS-tiled transpose (coalesced both sides)
__global__ __launch_bounds__(256) void gn_apply_t(const float* __restrict__ x,
    const float* __restrict__ stats, const float* __restrict__ sc, const float* __restrict__ bi,
    u16* __restrict__ hp){
  __shared__ u16 tile[64][66];
  int vb = blockIdx.x, cb = blockIdx.y, b = blockIdx.z;
  int t = threadIdx.x, w = t>>6, l = t&63;
  int v0 = vb*64, c0 = cb*64;
  const float* xb = x + (size_t)b*FD*LV;
  #pragma unroll
  for (int p=0;p<16;p++){
    int cc = p*4 + w;
    int c = c0 + cc;
    float val = xb[(size_t)c*LV + v0 + l];
    int g = c>>4;
    float m = stats[b*32+g];
    float r = stats[256 + b*32+g];
    float xn = (val - m)*r*sc[c] + bi[c];
    tile[cc][l] = f2b(xn / (1.f + expf(-xn)));
  }
  __syncthreads();
  u16* hpb = hp + (size_t)b*PV*FD;
  #pragma unroll
  for (int p=0;p<16;p++){
    int vv = p*4 + w;
    int v = v0 + vv;
    int z = v>>8, y = (v>>4)&15, xx = v&15;
    size_t hrow = ((size_t)(z+1)*324 + (size_t)(y+1)*18 + (xx+1))*FD;
    hpb[hrow + c0 + l] = tile[l][vv];
  }
}

// ---------------- conv as MFMA implicit GEMM: 2-phase double-buffer, counted vmcnt ----------------
__global__ __launch_bounds__(256,2) void conv_mfma(const u16* __restrict__ hp,
    const u16* __restrict__ wt, const float* __restrict__ cbias,
    const float* __restrict__ vpe, u16* __restrict__ qb){
  __shared__ __align__(16) u16 Al[16384];   // 2 bufs x 128 rows x 64 cols
  __shared__ __align__(16) u16 Wl[16384];
  int tid = threadIdx.x;
  int w = tid>>6, l = tid&63;
  int v0 = blockIdx.x*128, n0 = blockIdx.y*128, b = blockIdx.z;
  int swz = ((l&7) ^ ((l>>3)&7))*8;       // pre-swizzled source chunk (elems)
  size_t abase[4], wbase[4];
  int lrow[4];
  #pragma unroll
  for (int j=0;j<4;j++){
    int r = w*32 + j*8 + (l>>3);
    int v = v0 + r;
    int z = v>>8, yy=(v>>4)&15, xx=v&15;
    abase[j] = ((size_t)b*PV + (size_t)(z*324 + yy*18 + xx))*FD + swz;
    wbase[j] = (size_t)(n0 + r)*FD + swz;
    lrow[j] = (w*32 + j*8)*64;
  }
  f32x4 zero4 = {0.f,0.f,0.f,0.f};
  f32x4 acc[4][4];
  #pragma unroll
  for (int i=0;i<4;i++)
    #pragma unroll
    for (int j=0;j<4;j++) acc[i][j] = zero4;
  int wr = (w>>1)*64, wc = (w&1)*64;

  // prologue: stage K-step 0 into buf 0
  {
    #pragma unroll
    for (int j=0;j<4;j++){
      g2l(hp + abase[j], Al + lrow[j]);            // off=0 => adelta=0
      g2l(wt + wbase[j], Wl + lrow[j]);
    }
  }
  for (int kk=0; kk<216; ++kk){
    int cur = kk & 1;
    int nbuf = (cur^1)*8192;
    if (kk < 215){
      int kn = kk + 1;
      int off = kn>>3;
      int ks  = (kn&7)<<6;
      int dz = off/9; int rem = off - dz*9; int dy = rem/3; int dx = rem - dy*3;
      size_t adelta = (size_t)(dz*324 + dy*18 + dx)*FD + ks;
      size_t wdelta = (size_t)off*262144 + ks;
      #pragma unroll
      for (int j=0;j<4;j++){
        g2l(hp + abase[j] + adelta, Al + nbuf + lrow[j]);
        g2l(wt + wbase[j] + wdelta, Wl + nbuf + lrow[j]);
      }
      asm volatile("s_waitcnt vmcnt(8)" ::: "memory");   // current buf's 8 loads done; 8 in flight
    } else {
      asm volatile("s_waitcnt vmcnt(0)" ::: "memory");
    }
    __builtin_amdgcn_s_barrier();
    int cb0 = cur*8192;
    #pragma unroll
    for (int ks2=0; ks2<2; ++ks2){
      bfrag af[4], wf[4];
      #pragma unroll
      for (int i=0;i<4;i++){
        int ra = wr + i*16 + (l&15);
        af[i] = *(const bfrag*)(Al + cb0 + ra*64 + (((ks2<<2) + (l>>4)) ^ (l&7))*8);
        int rb = wc + i*16 + (l&15);
        wf[i] = *(const bfrag*)(Wl + cb0 + rb*64 + (((ks2<<2) + (l>>4)) ^ (l&7))*8);
      }
      #pragma unroll
      for (int i=0;i<4;i++)
        #pragma unroll
        for (int j=0;j<4;j++)
          acc[i][j] = __builtin_amdgcn_mfma_f32_16x16x32_bf16(af[i], wf[j], acc[i][j], 0,0,0);
    }
    __builtin_amdgcn_sched_barrier(0);
    __builtin_amdgcn_s_barrier();
  }
  #pragma unroll
  for (int i=0;i<4;i++)
    #pragma unroll
    for (int j=0;j<4;j++)
      #pragma unroll
      for (int rg=0;rg<4;rg++){
        int row = wr + i*16 + ((l>>4)<<2) + rg;
        int col = wc + j*16 + (l&15);
        int v = v0 + row, n = n0 + col;
        float cv = acc[i][j][rg] + cbias[n] + vpe[(size_t)v*FD + n];
        qb[((size_t)b*LV + v)*FD + n] = f2b(cv);
      }
}

// ---------------- MFMA TN GEMM, BK=64 (z=b): A[b][4096x512] @ W[512x512]^T + bias ----------------
template<bool TRANS>
__global__ __launch_bounds__(256,4) void gemm_mfma(const u16* __restrict__ A, const u16* __restrict__ W,
    const float* __restrict__ bias, void* __restrict__ Cout){
  __shared__ __align__(16) u16 Al[8192];   // 128 rows x 64 cols
  __shared__ __align__(16) u16 Wl[8192];
  int tid = threadIdx.x;
  int w = tid>>6, l = tid&63;
  int m0 = blockIdx.x*128, n0 = blockIdx.y*128, b = blockIdx.z;
  int swz = ((l&7) ^ ((l>>3)&7))*8;
  size_t abase[4], wbase[4];
  #pragma unroll
  for (int j=0;j<4;j++){
    int r = w*32 + j*8 + (l>>3);
    abase[j] = ((size_t)b*LV + m0 + r)*FD + swz;
    wbase[j] = (size_t)(n0 + r)*FD + swz;
  }
  f32x4 zero4 = {0.f,0.f,0.f,0.f};
  f32x4 acc[4][4];
  #pragma unroll
  for (int i=0;i<4;i++)
    #pragma unroll
    for (int j=0;j<4;j++) acc[i][j] = zero4;
  int wr = (w>>1)*64, wc = (w&1)*64;
  for (int kk=0; kk<8; ++kk){
    size_t kd = (size_t)kk*64;
    #pragma unroll
    for (int j=0;j<4;j++){
      g2l(A + abase[j] + kd, Al + (w*32 + j*8)*64);
      g2l(W + wbase[j] + kd, Wl + (w*32 + j*8)*64);
    }
    __syncthreads();
    #pragma unroll
    for (int ks2=0; ks2<2; ++ks2){
      bfrag af[4], wf[4];
      #pragma unroll
      for (int i=0;i<4;i++){
        int ra = wr + i*16 + (l&15);
        af[i] = *(const bfrag*)(Al + ra*64 + (((ks2<<2) + (l>>4)) ^ (l&7))*8);
        int rb = wc + i*16 + (l&15);
        wf[i] = *(const bfrag*)(Wl + rb*64 + (((ks2<<2) + (l>>4)) ^ (l&7))*8);
      }
      #pragma unroll
      for (int i=0;i<4;i++)
        #pragma unroll
        for (int j=0;j<4;j++)
          acc[i][j] = __builtin_amdgcn_mfma_f32_16x16x32_bf16(af[i], wf[j], acc[i][j], 0,0,0);
    }
    __syncthreads();
  }
  #pragma unroll
  for (int i=0;i<4;i++)
    #pragma unroll
    for (int j=0;j<4;j++){
      if constexpr (TRANS){
        int row = m0 + wr + i*16 + ((l>>4)<<2);
        int col = n0 + wc + j*16 + (l&15);
        float bv = bias[col];
        float4 val = { acc[i][j][0]+bv, acc[i][j][1]+bv, acc[i][j][2]+bv, acc[i][j][3]+bv };
        *(float4*)&(((float*)Cout)[((size_t)b*FD + col)*LV + row]) = val;
      } else {
        #pragma unroll
        for (int rg=0;rg<4;rg++){
          int row = m0 + wr + i*16 + ((l>>4)<<2) + rg;
          int col = n0 + wc + j*16 + (l&15);
          ((u16*)Cout)[((size_t)b*LV + row)*FD + col] = f2b(acc[i][j][rg] + bias[col]);
        }
      }
    }
}

// ---------------- merged K/V MFMA GEMM (z selects K- or V-path): C[1664][512] bf16 ----------------
template<bool ADDPE>
__global__ __launch_bounds__(256,2) void gemm_kv(const u16* __restrict__ A0, const u16* __restrict__ A1,
    const u16* __restrict__ W0, const u16* __restrict__ W1,
    const float* __restrict__ b0, const float* __restrict__ b1,
    const float* __restrict__ pe, u16* __restrict__ C0, u16* __restrict__ C1, int K){
  const u16* A = blockIdx.z ? A1 : A0;
  const u16* W = blockIdx.z ? W1 : W0;
  const float* bias = blockIdx.z ? b1 : b0;
  u16* Cout = blockIdx.z ? C1 : C0;
  __shared__ __align__(16) u16 Al[4096];
  __shared__ __align__(16) u16 Wl[4096];
  int tid = threadIdx.x;
  int w = tid>>6, l = tid&63;
  int m0 = blockIdx.x*128, n0 = blockIdx.y*128;
  int sw_src = (((l&3) ^ ((l>>3)&3)))*8;
  int sw_rd  = (((l>>4) ^ ((l>>1)&3)))*8;
  size_t abase[2], wbase[2];
  #pragma unroll
  for (int j=0;j<2;j++){
    int r = (w*2+j)*16 + (l>>2);
    abase[j] = (size_t)(m0 + r)*K + sw_src;
    wbase[j] = (size_t)(n0 + r)*K + sw_src;
  }
  f32x4 zero4 = {0.f,0.f,0.f,0.f};
  f32x4 acc[4][4];
  #pragma unroll
  for (int i=0;i<4;i++)
    #pragma unroll
    for (int j=0;j<4;j++) acc[i][j] = zero4;
  int wr = (w>>1)*64, wc = (w&1)*64;
  for (int k0=0; k0<K; k0+=32){
    #pragma unroll
    for (int j=0;j<2;j++){
      g2l(A + abase[j] + k0, Al + (w*2+j)*512);
      g2l(W + wbase[j] + k0, Wl + (w*2+j)*512);
    }
    __syncthreads();
    bfrag af[4], wf[4];
    #pragma unroll
    for (int i=0;i<4;i++){
      int r  = wr + i*16 + (l&15);
      af[i] = *(const bfrag*)(Al + r*32 + sw_rd);
      int cn = wc + i*16 + (l&15);
      wf[i] = *(const bfrag*)(Wl + cn*32 + sw_rd);
    }
    #pragma unroll
    for (int i=0;i<4;i++)
      #pragma unroll
      for (int j=0;j<4;j++)
        acc[i][j] = __builtin_amdgcn_mfma_f32_16x16x32_bf16(af[i], wf[j], acc[i][j], 0,0,0);
    __syncthreads();
  }
  #pragma unroll
  for (int i=0;i<4;i++)
    #pragma unroll
    for (int j=0;j<4;j++)
      #pragma unroll
      for (int rg=0;rg<4;rg++){
        int row = m0 + wr + i*16 + ((l>>4)<<2) + rg;
        int col = n0 + wc + j*16 + (l&15);
        float cv = acc[i][j][rg] + bias[col];
        if constexpr (ADDPE) cv += pe[(size_t)(row % 196)*FD + col];
        Cout[(size_t)row*FD + col] = f2b(cv);
      }
}

// ---------------- attention: wave = 4x4x4 voxel cube; LDS-transposed output ----------------
__global__ __launch_bounds__(256) void attn_lit(const u16* __restrict__ qh,
    const u16* __restrict__ khb, const u16* __restrict__ vhb,
    const u64* __restrict__ maskb, u16* __restrict__ obuf){
  __shared__ u16 ot[4][64][66];
  int t = threadIdx.x, w = t>>6, l = t&63;
  int h = blockIdx.y, b = blockIdx.z;
  int cube = blockIdx.x*4 + w;
  int cz = cube>>4, cy = (cube>>2)&3, cx = cube&3;
  int v = (cz*4 + (l>>4))*256 + (cy*4 + ((l>>2)&3))*16 + (cx*4 + (l&3));
  int cl = cube*64 + l;
  const u64* mrow = maskb + ((size_t)b*LV + cl)*4;
  u64 abits[4] = {mrow[0], mrow[1], mrow[2], mrow[3]};

  float qr[64];
  {
    const uint4* qp = (const uint4*)(qh + ((size_t)b*LV + v)*FD + h*64);
    #pragma unroll
    for (int c=0;c<8;c++){
      uint4 u = qp[c];
      qr[c*8+0]=b2f((u16)(u.x&0xffffu)); qr[c*8+1]=b2f((u16)(u.x>>16));
      qr[c*8+2]=b2f((u16)(u.y&0xffffu)); qr[c*8+3]=b2f((u16)(u.y>>16));
      qr[c*8+4]=b2f((u16)(u.z&0xffffu)); qr[c*8+5]=b2f((u16)(u.z>>16));
      qr[c*8+6]=b2f((u16)(u.w&0xffffu)); qr[c*8+7]=b2f((u16)(u.w>>16));
    }
  }
  const u16* kb = khb + (size_t)(b*196)*FD + h*64;
  const u16* vb = vhb + (size_t)(b*196)*FD + h*64;
  float o[64];
  #pragma unroll
  for (int d=0;d<64;d++) o[d]=0.f;
  float ssum = 0.f;
  for (int s=0;s<196;s++){
    if (!((abits[s>>6] >> (s&63)) & 1ull)) continue;
    const uint4* kr = (const uint4*)(kb + (size_t)s*FD);
    float dot = 0.f;
    #pragma unroll
    for (int c=0;c<8;c++){
      uint4 u = kr[c];
      dot += qr[c*8+0]*b2f((u16)(u.x&0xffffu)) + qr[c*8+1]*b2f((u16)(u.x>>16))
           + qr[c*8+2]*b2f((u16)(u.y&0xffffu)) + qr[c*8+3]*b2f((u16)(u.y>>16))
           + qr[c*8+4]*b2f((u16)(u.z&0xffffu)) + qr[c*8+5]*b2f((u16)(u.z>>16))
           + qr[c*8+6]*b2f((u16)(u.w&0xffffu)) + qr[c*8+7]*b2f((u16)(u.w>>16));
    }
    float e = expf(dot*0.125f);
    ssum += e;
    const uint4* vr = (const uint4*)(vb + (size_t)s*FD);
    #pragma unroll
    for (int c=0;c<8;c++){
      uint4 u = vr[c];
      o[c*8+0] += e*b2f((u16)(u.x&0xffffu)); o[c*8+1] += e*b2f((u16)(u.x>>16));
      o[c*8+2] += e*b2f((u16)(u.y&0xffffu)); o[c*8+3] += e*b2f((u16)(u.y>>16));
      o[c*8+4] += e*b2f((u16)(u.z&0xffffu)); o[c*8+5] += e*b2f((u16)(u.z>>16));
      o[c*8+6] += e*b2f((u16)(u.w&0xffffu)); o[c*8+7] += e*b2f((u16)(u.w>>16));
    }
  }
  float inv = (ssum > 0.f) ? 1.f/ssum : 0.f;
  u32* orow = (u32*)&ot[w][l][0];
  #pragma unroll
  for (int c=0;c<32;c++){
    u32 lo = f2b(o[c*2]*inv);
    u32 hi = f2b(o[c*2+1]*inv);
    orow[c] = lo | (hi<<16);
  }
  #pragma unroll 4
  for (int s=0;s<64;s++){
    int vs = (cz*4 + (s>>4))*256 + (cy*4 + ((s>>2)&3))*16 + (cx*4 + (s&3));
    obuf[((size_t)b*LV + vs)*FD + h*64 + l] = ot[w][s][l];
  }
}

extern "C" void kernel_launch(void* const* d_in, const int* in_sizes, int n_in,
                              void* d_out, int out_size, void* d_ws, size_t ws_size,
                              hipStream_t stream) {
  (void)in_sizes; (void)n_in; (void)out_size; (void)ws_size;
  const float* x_in  = (const float*)d_in[0];
  const float* sketch= (const float*)d_in[1];
  const float* projm = (const float*)d_in[2];
  const float* gnsc  = (const float*)d_in[3];
  const float* gnbi  = (const float*)d_in[4];
  const float* convw = (const float*)d_in[5];
  const float* convb = (const float*)d_in[6];
  const float* kw_in = (const float*)d_in[7];
  const float* kb_in = (const float*)d_in[8];
  const float* vw_in = (const float*)d_in[9];
  const float* vb_in = (const float*)d_in[10];
  const float* ipw   = (const float*)d_in[11];
  const float* ipb   = (const float*)d_in[12];
  const float* ow_in = (const float*)d_in[13];
  const float* ob_in = (const float*)d_in[14];
  char* ws = (char*)d_ws;
  u16*   wt   = (u16*)(ws + o_wt);
  u16*   Wq   = (u16*)(ws + o_wq);
  u16*   Ow   = (u16*)(ws + o_ow);
  float* vpe  = (float*)(ws + o_vpe);
  float* cpe  = (float*)(ws + o_cpe);
  float* stats= (float*)(ws + o_gn);
  u64*   maskb= (u64*)(ws + o_mask);
  u16*   khb  = (u16*)(ws + o_khb);
  u16*   vhb  = (u16*)(ws + o_vhb);
  u16*   hp   = (u16*)(ws + o_hp);
  u16*   qb   = (u16*)(ws + o_qb);
  u16*   qhb  = (u16*)(ws + o_qh);
  u16*   Skb  = (u16*)(ws + o_skb);
  u16*   Kwb  = (u16*)(ws + o_kwb);
  u16*   Vwb  = (u16*)(ws + o_vwb);
  u16*   Wkb  = (u16*)(ws + o_wkb);
  u16*   Wvb  = (u16*)(ws + o_wvb);
  u16*   ktb  = (u16*)(ws + o_ktb);
  u16*   vtb  = (u16*)(ws + o_vtb);
  u16*   obuf = qb;   // qb dead after q-proj

  hipMemsetAsync(hp, 0, 47775744, stream);
  hipMemsetAsync((char*)Skb + 2408448, 0, 147456, stream);   // pad sketch rows 1568..1663
  prep_all<<<12896,256,0,stream>>>(convw, ipw, ow_in, sketch, kw_in, vw_in,
                                   wt, Wq, Ow, Skb, Kwb, Vwb, Wkb, Wvb);
  geom_prep<<<4420,256,0,stream>>>(vpe, cpe, projm, maskb);
  gn_stats<<<256,256,0,stream>>>(x_in, stats);
  gemm_kv<true ><<<dim3(13,4,2),256,0,stream>>>(Skb, Skb, Kwb, Vwb, kb_in, vb_in, cpe, ktb, vtb, 768);
  gemm_kv<false><<<dim3(13,4,2),256,0,stream>>>(ktb, vtb, Wkb, Wvb, ipb+512, ipb+1024, nullptr, khb, vhb, 512);

  gn_apply_t<<<dim3(64,8,8),256,0,stream>>>(x_in, stats, gnsc, gnbi, hp);
  conv_mfma<<<dim3(32,4,8),256,0,stream>>>(hp, wt, convb, vpe, qb);
  gemm_mfma<false><<<dim3(32,4,8),256,0,stream>>>(qb, Wq, ipb, qhb);
  attn_lit<<<dim3(16,8,8),256,0,stream>>>(qhb, khb, vhb, maskb, obuf);
  gemm_mfma<true ><<<dim3(32,4,8),256,0,stream>>>(obuf, Ow, ob_in, d_out);
}

// Round 18
// 687.469 us; speedup vs baseline: 1.2155x; 1.2155x over previous
//
#include <hip/hip_runtime.h>

#define DEV static __device__ __forceinline__

typedef unsigned short u16;
typedef unsigned int u32;
typedef unsigned long long u64;
typedef float f32x4 __attribute__((ext_vector_type(4)));
typedef short bfrag __attribute__((ext_vector_type(8)));

#define FD 512
#define LV 4096
#define PV 5832   // 18^3

DEV float b2f(u16 u){ union{ u32 i; float f; } x; x.i = ((u32)u)<<16; return x.f; }
DEV u16 f2b(float f){ union{ float f; u32 i; } x; x.f = f; u32 r = x.i; r += 0x7fffu + ((r>>16)&1u); return (u16)(r>>16); }

DEV void g2l(const void* g, void* s){
  __builtin_amdgcn_global_load_lds((const __attribute__((address_space(1))) void*)g,
                                   (__attribute__((address_space(3))) void*)s, 16, 0, 0);
}

// ---------------- ws layout (bytes) ----------------
static const size_t o_wt  = 0;          // 27*512*512*2 conv weights bf16 [off][o][i]
static const size_t o_wq  = 14155776;   // 512*512*2
static const size_t o_ow  = 14680064;   // 512*512*2
static const size_t o_vpe = 15204352;   // 4096*512*4
static const size_t o_cpe = 23592960;   // 196*512*4
static const size_t o_gn  = 23994368;   // 512*4 stats
static const size_t o_mask= 23996416;   // 8*4096*4*8 mask bits (cube-linear)
static const size_t o_khb = 25044992;   // 1664*512*2 bf16 kh
static const size_t o_vhb = 26748928;   // 1664*512*2 bf16 vh
static const size_t o_hp  = 36841472;   // 8*5832*512*2 bf16
static const size_t o_qb  = 84617216;   // 8*4096*512*2 bf16 (q; obuf alias)
static const size_t o_qh  = 118171648;  // 8*4096*512*2 bf16 (q-proj)
static const size_t o_skb = o_qh;               // 1664*768*2
static const size_t o_kwb = o_qh + 2555904;
static const size_t o_vwb = o_qh + 3342336;
static const size_t o_wkb = o_qh + 4128768;
static const size_t o_wvb = o_qh + 4653056;
static const size_t o_ktb = o_qh + 5177344;     // 1664*512*2
static const size_t o_vtb = o_qh + 6881280;
// end = 151,726,080

// ================= setup1: prep_all + geom_prep + gn_stats =================
__global__ __launch_bounds__(256) void setup1(const float* __restrict__ convw,
    const float* __restrict__ ipw, const float* __restrict__ ow,
    const float* __restrict__ sketch, const float* __restrict__ kw, const float* __restrict__ vw,
    u16* __restrict__ wt, u16* __restrict__ Wq, u16* __restrict__ Ow, u16* __restrict__ Skb,
    u16* __restrict__ Kwb, u16* __restrict__ Vwb, u16* __restrict__ Wkb, u16* __restrict__ Wvb,
    float* __restrict__ vpe, float* __restrict__ cpe,
    const float* __restrict__ proj, u64* __restrict__ maskb,
    const float* __restrict__ x, float* __restrict__ stats){
  __shared__ float raw[6912];
  __shared__ float red[8];
  int blk = blockIdx.x, t = threadIdx.x;
  if (blk < 12896){
    // ---- prep_all ----
    if (blk < 1024){
      size_t base = (size_t)blk*6912;
      #pragma unroll
      for (int j=0;j<27;j++) raw[j*256 + t] = convw[base + j*256 + t];
      __syncthreads();
      int rowb = blk*256;
      #pragma unroll
      for (int k=0;k<27;k++) wt[(size_t)k*262144 + rowb + t] = f2b(raw[t*27 + k]);
    } else if (blk < 2048){ int i=(blk-1024)*256+t;  Wq[i]  = f2b(ipw[i]); }
    else if (blk < 3072){   int i=(blk-2048)*256+t;  Ow[i]  = f2b(ow[i]); }
    else if (blk < 7776){   int i=(blk-3072)*256+t;  if (i<1204224) Skb[i] = f2b(sketch[i]); }
    else if (blk < 9312){   int i=(blk-7776)*256+t;  Kwb[i] = f2b(kw[i]); }
    else if (blk < 10848){  int i=(blk-9312)*256+t;  Vwb[i] = f2b(vw[i]); }
    else if (blk < 11872){  int i=(blk-10848)*256+t; Wkb[i] = f2b(ipw[262144+i]); }
    else {                  int i=(blk-11872)*256+t; Wvb[i] = f2b(ipw[524288+i]); }
    return;
  }
  if (blk < 17316){
    // ---- geom_prep ----
    int gb = blk - 12896;
    if (gb < 4292){
      float* pe = (gb < 4096) ? vpe : cpe;
      int l = (gb < 4096) ? gb : gb - 4096;
      const float fac = -0.017988946039015984f;
      float dt = expf((float)(2*t) * fac);
      float ang = (float)l * dt;
      pe[(size_t)l*FD + 2*t]     = sinf(ang);
      pe[(size_t)l*FD + 2*t + 1] = cosf(ang);
      return;
    }
    int idx = (gb-4292)*256 + t;   // 8*4096
    int b = idx >> 12, v = idx & 4095;
    float P[9];
    #pragma unroll
    for (int j=0;j<9;j++) P[j] = proj[b*9 + j];
    int zi=v>>8, yi=(v>>4)&15, xi=v&15;
    float pt0 = ((float)zi + 0.5f)/16.0f - 0.5f;
    float pt1 = ((float)yi + 0.5f)/16.0f - 0.5f;
    float pt2 = ((float)xi + 0.5f)/16.0f - 0.5f;
    float pc0 = __fadd_rn(__fadd_rn(__fmul_rn(P[0],pt0), __fmul_rn(P[1],pt1)), __fmul_rn(P[2],pt2));
    float pc1 = __fadd_rn(__fadd_rn(__fmul_rn(P[3],pt0), __fmul_rn(P[4],pt1)), __fmul_rn(P[5],pt2));
    float pc2 = __fadd_rn(__fadd_rn(__fmul_rn(P[6],pt0), __fmul_rn(P[7],pt1)), __fmul_rn(P[8],pt2));
    float r0 = __fdiv_rn(pc0, pc2);
    float r1 = __fdiv_rn(pc1, pc2);
    float px0 = fminf(fmaxf(rintf(r0), 0.f), 223.f);
    float px1 = fminf(fmaxf(rintf(r1), 0.f), 223.f);
    float x_idx = __fmul_rn(__fdiv_rn(__fadd_rn(__fmul_rn(2.f,px1),1.f), 224.f), 14.f) * 0.5f;
    float y_idx = __fmul_rn(__fdiv_rn(__fadd_rn(__fmul_rn(2.f,__fadd_rn(223.f,-px0)),1.f), 224.f), 14.f) * 0.5f;
    float ps0 = __fadd_rn(x_idx, -0.5f);
    float ps1 = __fadd_rn(y_idx, -0.5f);
    const float TH = 1.4999990463256836f;
    u64 abits[4] = {0,0,0,0};
    #pragma unroll 1
    for (int s=0;s<196;s++){
      int si = s/14, sj = s - si*14;
      float d0 = __fadd_rn(ps0, -(float)si);
      float d1 = __fadd_rn(ps1, -(float)sj);
      float dist = sqrtf(__fadd_rn(__fmul_rn(d0,d0), __fmul_rn(d1,d1)));
      if (!(fabsf(dist) > TH)) abits[s>>6] |= (1ull << (s&63));
    }
    int cube = (zi>>2)*16 + (yi>>2)*4 + (xi>>2);
    int cl = cube*64 + (zi&3)*16 + (yi&3)*4 + (xi&3);
    u64* out = maskb + ((size_t)b*4096 + cl)*4;
    out[0]=abits[0]; out[1]=abits[1]; out[2]=abits[2]; out[3]=abits[3];
    return;
  }
  // ---- gn_stats ----
  {
    int bg = blk - 17316;
    const float* base = x + (size_t)bg*65536;
    float s=0.f, q=0.f;
    for (int i=t;i<65536;i+=256){ float v = base[i]; s+=v; q+=v*v; }
    #pragma unroll
    for (int off=32; off>0; off>>=1){ s += __shfl_xor(s,off); q += __shfl_xor(q,off); }
    int w = t>>6;
    if ((t&63)==0){ red[w*2]=s; red[w*2+1]=q; }
    __syncthreads();
    if (t==0){
      float S=red[0]+red[2]+red[4]+red[6];
      float Q=red[1]+red[3]+red[5]+red[7];
      float m = S*(1.f/65536.f);
      float var = Q*(1.f/65536.f) - m*m;
      stats[bg] = m;
      stats[256+bg] = rsqrtf(var + 1e-5f);
    }
  }
}

// ---------------- kv GEMM body (shared-mem passed in) ----------------
template<bool ADDPE>
DEV void kv_body(int bx, int by, int bz,
    const u16* __restrict__ A0, const u16* __restrict__ A1,
    const u16* __restrict__ W0, const u16* __restrict__ W1,
    const float* __restrict__ b0, const float* __restrict__ b1,
    const float* __restrict__ pe, u16* __restrict__ C0, u16* __restrict__ C1, int K,
    u16* Al, u16* Wl){
  const u16* A = bz ? A1 : A0;
  const u16* W = bz ? W1 : W0;
  const float* bias = bz ? b1 : b0;
  u16* Cout = bz ? C1 : C0;
  int tid = threadIdx.x;
  int w = tid>>6, l = tid&63;
  int m0 = bx*128, n0 = by*128;
  int sw_src = (((l&3) ^ ((l>>3)&3)))*8;
  int sw_rd  = (((l>>4) ^ ((l>>1)&3)))*8;
  size_t abase[2], wbase[2];
  #pragma unroll
  for (int j=0;j<2;j++){
    int r = (w*2+j)*16 + (l>>2);
    abase[j] = (size_t)(m0 + r)*K + sw_src;
    wbase[j] = (size_t)(n0 + r)*K + sw_src;
  }
  f32x4 zero4 = {0.f,0.f,0.f,0.f};
  f32x4 acc[4][4];
  #pragma unroll
  for (int i=0;i<4;i++)
    #pragma unroll
    for (int j=0;j<4;j++) acc[i][j] = zero4;
  int wr = (w>>1)*64, wc = (w&1)*64;
  for (int k0=0; k0<K; k0+=32){
    #pragma unroll
    for (int j=0;j<2;j++){
      g2l(A + abase[j] + k0, Al + (w*2+j)*512);
      g2l(W + wbase[j] + k0, Wl + (w*2+j)*512);
    }
    __syncthreads();
    bfrag af[4], wf[4];
    #pragma unroll
    for (int i=0;i<4;i++){
      int r  = wr + i*16 + (l&15);
      af[i] = *(const bfrag*)(Al + r*32 + sw_rd);
      int cn = wc + i*16 + (l&15);
      wf[i] = *(const bfrag*)(Wl + cn*32 + sw_rd);
    }
    #pragma unroll
    for (int i=0;i<4;i++)
      #pragma unroll
      for (int j=0;j<4;j++)
        acc[i][j] = __builtin_amdgcn_mfma_f32_16x16x32_bf16(af[i], wf[j], acc[i][j], 0,0,0);
    __syncthreads();
  }
  #pragma unroll
  for (int i=0;i<4;i++)
    #pragma unroll
    for (int j=0;j<4;j++)
      #pragma unroll
      for (int rg=0;rg<4;rg++){
        int row = m0 + wr + i*16 + ((l>>4)<<2) + rg;
        int col = n0 + wc + j*16 + (l&15);
        float cv = acc[i][j][rg] + bias[col];
        if constexpr (ADDPE) cv += pe[(size_t)(row % 196)*FD + col];
        Cout[(size_t)row*FD + col] = f2b(cv);
      }
}

// ================= fuse2: kv stage-1 + gn_apply_t =================
__global__ __launch_bounds__(256,4) void fuse2(
    const u16* __restrict__ Skb, const u16* __restrict__ Kwb, const u16* __restrict__ Vwb,
    const float* __restrict__ kb, const float* __restrict__ vb, const float* __restrict__ cpe,
    u16* __restrict__ ktb, u16* __restrict__ vtb,
    const float* __restrict__ x, const float* __restrict__ stats,
    const float* __restrict__ sc, const float* __restrict__ bi, u16* __restrict__ hp){
  __shared__ __align__(16) u16 Al[4096];
  __shared__ __align__(16) u16 Wl[4096];
  __shared__ u16 tile[64][66];
  int blk = blockIdx.x;
  if (blk < 104){
    kv_body<true>(blk%13, (blk/13)%4, blk/52, Skb, Skb, Kwb, Vwb, kb, vb, cpe, ktb, vtb, 768, Al, Wl);
    return;
  }
  // ---- gn_apply_t ----
  int i = blk - 104;            // 4096 blocks: (64,8,8)
  int vb2 = i & 63, cb = (i>>6)&7, b = i>>9;
  int t = threadIdx.x, w = t>>6, l = t&63;
  int v0 = vb2*64, c0 = cb*64;
  const float* xb = x + (size_t)b*FD*LV;
  #pragma unroll
  for (int p=0;p<16;p++){
    int cc = p*4 + w;
    int c = c0 + cc;
    float val = xb[(size_t)c*LV + v0 + l];
    int g = c>>4;
    float m = stats[b*32+g];
    float r = stats[256 + b*32+g];
    float xn = (val - m)*r*sc[c] + bi[c];
    tile[cc][l] = f2b(xn / (1.f + expf(-xn)));
  }
  __syncthreads();
  u16* hpb = hp + (size_t)b*PV*FD;
  #pragma unroll
  for (int p=0;p<16;p++){
    int vv = p*4 + w;
    int v = v0 + vv;
    int z = v>>8, y = (v>>4)&15, xx = v&15;
    size_t hrow = ((size_t)(z+1)*324 + (size_t)(y+1)*18 + (xx+1))*FD;
    hpb[hrow + c0 + l] = tile[l][vv];
  }
}

// ================= fuse3: conv (BK=64, 4 blk/CU) + kv stage-2 =================
__global__ __launch_bounds__(256,4) void fuse3(const u16* __restrict__ hp,
    const u16* __restrict__ wt, const float* __restrict__ cbias,
    const float* __restrict__ vpe, u16* __restrict__ qb,
    const u16* __restrict__ ktb, const u16* __restrict__ vtb,
    const u16* __restrict__ Wkb, const u16* __restrict__ Wvb,
    const float* __restrict__ ipb, u16* __restrict__ khb, u16* __restrict__ vhb){
  __shared__ __align__(16) u16 Al[8192];   // conv: full; kv2: first 4096
  __shared__ __align__(16) u16 Wl[8192];
  int blk = blockIdx.x;
  if (blk >= 1024){
    int i = blk - 1024;   // 104 blocks: (13,4,2)
    kv_body<false>(i%13, (i/13)%4, i/52, ktb, vtb, Wkb, Wvb, ipb+512, ipb+1024, nullptr, khb, vhb, 512, Al, Wl);
    return;
  }
  // ---- conv (R16 verbatim) ----
  int tid = threadIdx.x;
  int w = tid>>6, l = tid&63;
  int v0 = (blk & 31)*128, n0 = ((blk>>5)&3)*128, b = blk>>7;
  int swz = ((l&7) ^ ((l>>3)&7))*8;
  size_t abase[4], wbase[4];
  #pragma unroll
  for (int j=0;j<4;j++){
    int r = w*32 + j*8 + (l>>3);
    int v = v0 + r;
    int z = v>>8, yy=(v>>4)&15, xx=v&15;
    abase[j] = ((size_t)b*PV + (size_t)(z*324 + yy*18 + xx))*FD + swz;
    wbase[j] = (size_t)(n0 + r)*FD + swz;
  }
  f32x4 zero4 = {0.f,0.f,0.f,0.f};
  f32x4 acc[4][4];
  #pragma unroll
  for (int i=0;i<4;i++)
    #pragma unroll
    for (int j=0;j<4;j++) acc[i][j] = zero4;
  int wr = (w>>1)*64, wc = (w&1)*64;
  for (int kk=0; kk<216; ++kk){
    int off = kk>>3;
    int ks  = (kk&7)<<6;
    int dz = off/9; int rem = off - dz*9; int dy = rem/3; int dx = rem - dy*3;
    size_t adelta = (size_t)(dz*324 + dy*18 + dx)*FD + ks;
    size_t wdelta = (size_t)off*262144 + ks;
    #pragma unroll
    for (int j=0;j<4;j++){
      g2l(hp + abase[j] + adelta, Al + (w*32 + j*8)*64);
      g2l(wt + wbase[j] + wdelta, Wl + (w*32 + j*8)*64);
    }
    __syncthreads();
    #pragma unroll
    for (int ks2=0; ks2<2; ++ks2){
      bfrag af[4], wf[4];
      #pragma unroll
      for (int i=0;i<4;i++){
        int ra = wr + i*16 + (l&15);
        af[i] = *(const bfrag*)(Al + ra*64 + (((ks2<<2) + (l>>4)) ^ (l&7))*8);
        int rb = wc + i*16 + (l&15);
        wf[i] = *(const bfrag*)(Wl + rb*64 + (((ks2<<2) + (l>>4)) ^ (l&7))*8);
      }
      #pragma unroll
      for (int i=0;i<4;i++)
        #pragma unroll
        for (int j=0;j<4;j++)
          acc[i][j] = __builtin_amdgcn_mfma_f32_16x16x32_bf16(af[i], wf[j], acc[i][j], 0,0,0);
    }
    __syncthreads();
  }
  #pragma unroll
  for (int i=0;i<4;i++)
    #pragma unroll
    for (int j=0;j<4;j++)
      #pragma unroll
      for (int rg=0;rg<4;rg++){
        int row = wr + i*16 + ((l>>4)<<2) + rg;
        int col = wc + j*16 + (l&15);
        int v = v0 + row, n = n0 + col;
        float cv = acc[i][j][rg] + cbias[n] + vpe[(size_t)v*FD + n];
        qb[((size_t)b*LV + v)*FD + n] = f2b(cv);
      }
}

// ---------------- MFMA TN GEMM, BK=64 (z=b): A[b][4096x512] @ W[512x512]^T + bias ----------------
template<bool TRANS>
__global__ __launch_bounds__(256,4) void gemm_mfma(const u16* __restrict__ A, const u16* __restrict__ W,
    const float* __restrict__ bias, void* __restrict__ Cout){
  __shared__ __align__(16) u16 Al[8192];
  __shared__ __align__(16) u16 Wl[8192];
  int tid = threadIdx.x;
  int w = tid>>6, l = tid&63;
  int m0 = blockIdx.x*128, n0 = blockIdx.y*128, b = blockIdx.z;
  int swz = ((l&7) ^ ((l>>3)&7))*8;
  size_t abase[4], wbase[4];
  #pragma unroll
  for (int j=0;j<4;j++){
    int r = w*32 + j*8 + (l>>3);
    abase[j] = ((size_t)b*LV + m0 + r)*FD + swz;
    wbase[j] = (size_t)(n0 + r)*FD + swz;
  }
  f32x4 zero4 = {0.f,0.f,0.f,0.f};
  f32x4 acc[4][4];
  #pragma unroll
  for (int i=0;i<4;i++)
    #pragma unroll
    for (int j=0;j<4;j++) acc[i][j] = zero4;
  int wr = (w>>1)*64, wc = (w&1)*64;
  for (int kk=0; kk<8; ++kk){
    size_t kd = (size_t)kk*64;
    #pragma unroll
    for (int j=0;j<4;j++){
      g2l(A + abase[j] + kd, Al + (w*32 + j*8)*64);
      g2l(W + wbase[j] + kd, Wl + (w*32 + j*8)*64);
    }
    __syncthreads();
    #pragma unroll
    for (int ks2=0; ks2<2; ++ks2){
      bfrag af[4], wf[4];
      #pragma unroll
      for (int i=0;i<4;i++){
        int ra = wr + i*16 + (l&15);
        af[i] = *(const bfrag*)(Al + ra*64 + (((ks2<<2) + (l>>4)) ^ (l&7))*8);
        int rb = wc + i*16 + (l&15);
        wf[i] = *(const bfrag*)(Wl + rb*64 + (((ks2<<2) + (l>>4)) ^ (l&7))*8);
      }
      #pragma unroll
      for (int i=0;i<4;i++)
        #pragma unroll
        for (int j=0;j<4;j++)
          acc[i][j] = __builtin_amdgcn_mfma_f32_16x16x32_bf16(af[i], wf[j], acc[i][j], 0,0,0);
    }
    __syncthreads();
  }
  #pragma unroll
  for (int i=0;i<4;i++)
    #pragma unroll
    for (int j=0;j<4;j++){
      if constexpr (TRANS){
        int row = m0 + wr + i*16 + ((l>>4)<<2);
        int col = n0 + wc + j*16 + (l&15);
        float bv = bias[col];
        float4 val = { acc[i][j][0]+bv, acc[i][j][1]+bv, acc[i][j][2]+bv, acc[i][j][3]+bv };
        *(float4*)&(((float*)Cout)[((size_t)b*FD + col)*LV + row]) = val;
      } else {
        #pragma unroll
        for (int rg=0;rg<4;rg++){
          int row = m0 + wr + i*16 + ((l>>4)<<2) + rg;
          int col = n0 + wc + j*16 + (l&15);
          ((u16*)Cout)[((size_t)b*LV + row)*FD + col] = f2b(acc[i][j][rg] + bias[col]);
        }
      }
    }
}

// ---------------- attention: wave = 4x4x4 voxel cube; LDS-transposed output ----------------
__global__ __launch_bounds__(256) void attn_lit(const u16* __restrict__ qh,
    const u16* __restrict__ khb, const u16* __restrict__ vhb,
    const u64* __restrict__ maskb, u16* __restrict__ obuf){
  __shared__ u16 ot[4][64][66];
  int t = threadIdx.x, w = t>>6, l = t&63;
  int h = blockIdx.y, b = blockIdx.z;
  int cube = blockIdx.x*4 + w;
  int cz = cube>>4, cy = (cube>>2)&3, cx = cube&3;
  int v = (cz*4 + (l>>4))*256 + (cy*4 + ((l>>2)&3))*16 + (cx*4 + (l&3));
  int cl = cube*64 + l;
  const u64* mrow = maskb + ((size_t)b*LV + cl)*4;
  u64 abits[4] = {mrow[0], mrow[1], mrow[2], mrow[3]};

  float qr[64];
  {
    const uint4* qp = (const uint4*)(qh + ((size_t)b*LV + v)*FD + h*64);
    #pragma unroll
    for (int c=0;c<8;c++){
      uint4 u = qp[c];
      qr[c*8+0]=b2f((u16)(u.x&0xffffu)); qr[c*8+1]=b2f((u16)(u.x>>16));
      qr[c*8+2]=b2f((u16)(u.y&0xffffu)); qr[c*8+3]=b2f((u16)(u.y>>16));
      qr[c*8+4]=b2f((u16)(u.z&0xffffu)); qr[c*8+5]=b2f((u16)(u.z>>16));
      qr[c*8+6]=b2f((u16)(u.w&0xffffu)); qr[c*8+7]=b2f((u16)(u.w>>16));
    }
  }
  const u16* kb = khb + (size_t)(b*196)*FD + h*64;
  const u16* vb = vhb + (size_t)(b*196)*FD + h*64;
  float o[64];
  #pragma unroll
  for (int d=0;d<64;d++) o[d]=0.f;
  float ssum = 0.f;
  for (int s=0;s<196;s++){
    if (!((abits[s>>6] >> (s&63)) & 1ull)) continue;
    const uint4* kr = (const uint4*)(kb + (size_t)s*FD);
    float dot = 0.f;
    #pragma unroll
    for (int c=0;c<8;c++){
      uint4 u = kr[c];
      dot += qr[c*8+0]*b2f((u16)(u.x&0xffffu)) + qr[c*8+1]*b2f((u16)(u.x>>16))
           + qr[c*8+2]*b2f((u16)(u.y&0xffffu)) + qr[c*8+3]*b2f((u16)(u.y>>16))
           + qr[c*8+4]*b2f((u16)(u.z&0xffffu)) + qr[c*8+5]*b2f((u16)(u.z>>16))
           + qr[c*8+6]*b2f((u16)(u.w&0xffffu)) + qr[c*8+7]*b2f((u16)(u.w>>16));
    }
    float e = expf(dot*0.125f);
    ssum += e;
    const uint4* vr = (const uint4*)(vb + (size_t)s*FD);
    #pragma unroll
    for (int c=0;c<8;c++){
      uint4 u = vr[c];
      o[c*8+0] += e*b2f((u16)(u.x&0xffffu)); o[c*8+1] += e*b2f((u16)(u.x>>16));
      o[c*8+2] += e*b2f((u16)(u.y&0xffffu)); o[c*8+3] += e*b2f((u16)(u.y>>16));
      o[c*8+4] += e*b2f((u16)(u.z&0xffffu)); o[c*8+5] += e*b2f((u16)(u.z>>16));
      o[c*8+6] += e*b2f((u16)(u.w&0xffffu)); o[c*8+7] += e*b2f((u16)(u.w>>16));
    }
  }
  float inv = (ssum > 0.f) ? 1.f/ssum : 0.f;
  u32* orow = (u32*)&ot[w][l][0];
  #pragma unroll
  for (int c=0;c<32;c++){
    u32 lo = f2b(o[c*2]*inv);
    u32 hi = f2b(o[c*2+1]*inv);
    orow[c] = lo | (hi<<16);
  }
  #pragma unroll 4
  for (int s=0;s<64;s++){
    int vs = (cz*4 + (s>>4))*256 + (cy*4 + ((s>>2)&3))*16 + (cx*4 + (s&3));
    obuf[((size_t)b*LV + vs)*FD + h*64 + l] = ot[w][s][l];
  }
}

extern "C" void kernel_launch(void* const* d_in, const int* in_sizes, int n_in,
                              void* d_out, int out_size, void* d_ws, size_t ws_size,
                              hipStream_t stream) {
  (void)in_sizes; (void)n_in; (void)out_size; (void)ws_size;
  const float* x_in  = (const float*)d_in[0];
  const float* sketch= (const float*)d_in[1];
  const float* projm = (const float*)d_in[2];
  const float* gnsc  = (const float*)d_in[3];
  const float* gnbi  = (const float*)d_in[4];
  const float* convw = (const float*)d_in[5];
  const float* convb = (const float*)d_in[6];
  const float* kw_in = (const float*)d_in[7];
  const float* kb_in = (const float*)d_in[8];
  const float* vw_in = (const float*)d_in[9];
  const float* vb_in = (const float*)d_in[10];
  const float* ipw   = (const float*)d_in[11];
  const float* ipb   = (const float*)d_in[12];
  const float* ow_in = (const float*)d_in[13];
  const float* ob_in = (const float*)d_in[14];
  char* ws = (char*)d_ws;
  u16*   wt   = (u16*)(ws + o_wt);
  u16*   Wq   = (u16*)(ws + o_wq);
  u16*   Ow   = (u16*)(ws + o_ow);
  float* vpe  = (float*)(ws + o_vpe);
  float* cpe  = (float*)(ws + o_cpe);
  float* stats= (float*)(ws + o_gn);
  u64*   maskb= (u64*)(ws + o_mask);
  u16*   khb  = (u16*)(ws + o_khb);
  u16*   vhb  = (u16*)(ws + o_vhb);
  u16*   hp   = (u16*)(ws + o_hp);
  u16*   qb   = (u16*)(ws + o_qb);
  u16*   qhb  = (u16*)(ws + o_qh);
  u16*   Skb  = (u16*)(ws + o_skb);
  u16*   Kwb  = (u16*)(ws + o_kwb);
  u16*   Vwb  = (u16*)(ws + o_vwb);
  u16*   Wkb  = (u16*)(ws + o_wkb);
  u16*   Wvb  = (u16*)(ws + o_wvb);
  u16*   ktb  = (u16*)(ws + o_ktb);
  u16*   vtb  = (u16*)(ws + o_vtb);
  u16*   obuf = qb;   // qb dead after q-proj

  hipMemsetAsync(hp, 0, 47775744, stream);
  hipMemsetAsync((char*)Skb + 2408448, 0, 147456, stream);
  setup1<<<17572,256,0,stream>>>(convw, ipw, ow_in, sketch, kw_in, vw_in,
                                 wt, Wq, Ow, Skb, Kwb, Vwb, Wkb, Wvb,
                                 vpe, cpe, projm, maskb, x_in, stats);
  fuse2<<<4200,256,0,stream>>>(Skb, Kwb, Vwb, kb_in, vb_in, cpe, ktb, vtb,
                               x_in, stats, gnsc, gnbi, hp);
  fuse3<<<1128,256,0,stream>>>(hp, wt, convb, vpe, qb,
                               ktb, vtb, Wkb, Wvb, ipb, khb, vhb);
  gemm_mfma<false><<<dim3(32,4,8),256,0,stream>>>(qb, Wq, ipb, qhb);
  attn_lit<<<dim3(16,8,8),256,0,stream>>>(qhb, khb, vhb, maskb, obuf);
  gemm_mfma<true ><<<dim3(32,4,8),256,0,stream>>>(obuf, Ow, ob_in, d_out);
}